// Round 1
// baseline (499.987 us; speedup 1.0000x reference)
//
#include <hip/hip_runtime.h>
#include <math.h>

#define N_NODES 100000
#define R_REL   1000
#define T_TRI   600000
#define D_DIM   128
#define NDEPTH  2
#define OUT_STRIDE (D_DIM * (2 * NDEPTH + 1))   // 640

__device__ __forceinline__ float wave_sum(float v) {
    #pragma unroll
    for (int off = 32; off > 0; off >>= 1) v += __shfl_xor(v, off);
    return v;
}
__device__ __forceinline__ float wave_max(float v) {
    #pragma unroll
    for (int off = 32; off > 0; off >>= 1) v = fmaxf(v, __shfl_xor(v, off));
    return v;
}

// out[n, 0:128] = tanh(features[n, :])
__global__ void k_tanh(const float* __restrict__ feat, float* __restrict__ out) {
    int i = blockIdx.x * blockDim.x + threadIdx.x;          // over N*D/4
    if (i >= N_NODES * D_DIM / 4) return;
    int n  = i / (D_DIM / 4);
    int d4 = i % (D_DIM / 4);
    float4 v = reinterpret_cast<const float4*>(feat)[i];
    float4 o;
    o.x = tanhf(v.x); o.y = tanhf(v.y); o.z = tanhf(v.z); o.w = tanhf(v.w);
    reinterpret_cast<float4*>(out + (size_t)n * OUT_STRIDE)[d4] = o;
}

// per-relation: norm_r[r] = ||rel_emb[r]||,  dotk[l*R + r] = rel_emb[r] . attn_kernels[l]
__global__ void k_relprep(const float* __restrict__ rel, const float* __restrict__ attk,
                          float* __restrict__ norm_r, float* __restrict__ dotk) {
    int r = blockIdx.x;
    int lane = threadIdx.x;                                  // 64 threads
    float a0 = rel[r * D_DIM + lane], a1 = rel[r * D_DIM + 64 + lane];
    float nrm = wave_sum(a0 * a0 + a1 * a1);
    float d0  = wave_sum(a0 * attk[lane] + a1 * attk[64 + lane]);
    float d1  = wave_sum(a0 * attk[D_DIM + lane] + a1 * attk[D_DIM + 64 + lane]);
    if (lane == 0) {
        norm_r[r] = sqrtf(nrm);
        dotk[r] = d0;
        dotk[R_REL + r] = d1;
    }
}

// row_ptr[n] = lower_bound(rows, n) over sorted rows[0..T)
__global__ void k_rowptr(const int* __restrict__ rows, int* __restrict__ ptr) {
    int n = blockIdx.x * blockDim.x + threadIdx.x;
    if (n > N_NODES) return;
    int lo = 0, hi = T_TRI;
    while (lo < hi) { int mid = (lo + hi) >> 1; if (rows[mid] < n) lo = mid + 1; else hi = mid; }
    ptr[n] = lo;
}

// One wave per row: segment softmax over relation logits + Householder-reflected
// neighbor accumulate.  in/out chunks live inside the output buffer.
__global__ void k_nr_layer(float* __restrict__ outbuf, int in_off, int out_off,
                           const int* __restrict__ row_ptr,
                           const int* __restrict__ col,
                           const int* __restrict__ ridx1,
                           const float* __restrict__ r_val,
                           const float* __restrict__ rel,
                           const float* __restrict__ norm_r,
                           const float* __restrict__ dotk) {
    int gid  = blockIdx.x * blockDim.x + threadIdx.x;
    int wid  = gid >> 6;
    int lane = threadIdx.x & 63;
    if (wid >= N_NODES) return;
    int beg = row_ptr[wid], end = row_ptr[wid + 1];
    float* orow = outbuf + (size_t)wid * OUT_STRIDE + out_off;
    if (beg == end) { orow[lane] = 0.f; orow[lane + 64] = 0.f; return; }

    // pass A: segment max and sum of exp (logits are cheap scalars)
    float lmax = -INFINITY;
    for (int t = beg + lane; t < end; t += 64) {
        int rt = ridx1[t];
        float rv = r_val[t];
        float sc = rv / fmaxf(rv * norm_r[rt], 1e-12f);
        lmax = fmaxf(lmax, sc * dotk[rt]);
    }
    float m = wave_max(lmax);
    float lsum = 0.f;
    for (int t = beg + lane; t < end; t += 64) {
        int rt = ridx1[t];
        float rv = r_val[t];
        float sc = rv / fmaxf(rv * norm_r[rt], 1e-12f);
        lsum += expf(sc * dotk[rt] - m);
    }
    float inv_s = 1.f / wave_sum(lsum);

    // pass B: weighted reflected-neighbor accumulate (lane-parallel over D)
    float acc0 = 0.f, acc1 = 0.f;
    for (int t = beg; t < end; ++t) {
        int c  = col[t];
        int rt = ridx1[t];
        float rv = r_val[t];
        float sc = rv / fmaxf(rv * norm_r[rt], 1e-12f);
        float w  = expf(sc * dotk[rt] - m) * inv_s;
        const float* frow = outbuf + (size_t)c * OUT_STRIDE + in_off;
        float n0 = frow[lane], n1 = frow[lane + 64];
        float r0 = rel[rt * D_DIM + lane], r1 = rel[rt * D_DIM + 64 + lane];
        float rdot = wave_sum(n0 * r0 + n1 * r1);
        float f = 2.f * sc * sc * rdot;       // 2 * dot * sc, with dot = sc * rdot
        acc0 += w * (n0 - f * r0);
        acc1 += w * (n1 - f * r1);
    }
    orow[lane]      = tanhf(acc0);
    orow[lane + 64] = tanhf(acc1);
}

// proj[n] = feats[n] . high_atts[l]
__global__ void k_proj(const float* __restrict__ outbuf, int in_off,
                       const float* __restrict__ ha, float* __restrict__ proj) {
    int gid  = blockIdx.x * blockDim.x + threadIdx.x;
    int wid  = gid >> 6;
    int lane = threadIdx.x & 63;
    if (wid >= N_NODES) return;
    const float* frow = outbuf + (size_t)wid * OUT_STRIDE + in_off;
    float p = wave_sum(frow[lane] * ha[lane] + frow[lane + 64] * ha[64 + lane]);
    if (lane == 0) proj[wid] = p;
}

__global__ void k_high_layer(float* __restrict__ outbuf, int in_off, int out_off,
                             const int* __restrict__ row_ptr,
                             const int* __restrict__ hcol,
                             const float* __restrict__ proj) {
    int gid  = blockIdx.x * blockDim.x + threadIdx.x;
    int wid  = gid >> 6;
    int lane = threadIdx.x & 63;
    if (wid >= N_NODES) return;
    int beg = row_ptr[wid], end = row_ptr[wid + 1];
    float* orow = outbuf + (size_t)wid * OUT_STRIDE + out_off;
    if (beg == end) { orow[lane] = 0.f; orow[lane + 64] = 0.f; return; }

    float lmax = -INFINITY;
    for (int t = beg + lane; t < end; t += 64)
        lmax = fmaxf(lmax, proj[hcol[t]]);
    float m = wave_max(lmax);
    float lsum = 0.f;
    for (int t = beg + lane; t < end; t += 64)
        lsum += expf(proj[hcol[t]] - m);
    float inv_s = 1.f / wave_sum(lsum);

    float acc0 = 0.f, acc1 = 0.f;
    for (int t = beg; t < end; ++t) {
        int c = hcol[t];
        float w = expf(proj[c] - m) * inv_s;
        const float* frow = outbuf + (size_t)c * OUT_STRIDE + in_off;
        acc0 += w * frow[lane];
        acc1 += w * frow[lane + 64];
    }
    orow[lane]      = tanhf(acc0);
    orow[lane + 64] = tanhf(acc1);
}

extern "C" void kernel_launch(void* const* d_in, const int* in_sizes, int n_in,
                              void* d_out, int out_size, void* d_ws, size_t ws_size,
                              hipStream_t stream) {
    const float* features  = (const float*)d_in[0];
    const float* rel_emb   = (const float*)d_in[1];
    const float* r_val     = (const float*)d_in[2];
    const float* attk      = (const float*)d_in[3];
    const float* high_atts = (const float*)d_in[4];
    const int*   adj       = (const int*)d_in[5];   // [0..T) = row, [T..2T) = col
    const int*   r_index   = (const int*)d_in[6];   // [0..T) = arange, [T..2T) = rel id
    const int*   high_nei  = (const int*)d_in[7];
    float* out = (float*)d_out;

    char* ws = (char*)d_ws;
    int*   row_ptr_adj  = (int*)ws;   ws += (N_NODES + 1) * sizeof(int);
    int*   row_ptr_high = (int*)ws;   ws += (N_NODES + 1) * sizeof(int);
    float* norm_r       = (float*)ws; ws += R_REL * sizeof(float);
    float* dotk         = (float*)ws; ws += 2 * R_REL * sizeof(float);
    float* proj         = (float*)ws; ws += N_NODES * sizeof(float);

    k_tanh<<<(N_NODES * D_DIM / 4 + 255) / 256, 256, 0, stream>>>(features, out);
    k_relprep<<<R_REL, 64, 0, stream>>>(rel_emb, attk, norm_r, dotk);
    k_rowptr<<<(N_NODES + 256) / 256, 256, 0, stream>>>(adj, row_ptr_adj);
    k_rowptr<<<(N_NODES + 256) / 256, 256, 0, stream>>>(high_nei, row_ptr_high);

    int row_blocks = (N_NODES + 3) / 4;     // 4 waves (rows) per 256-thread block
    for (int l = 0; l < NDEPTH; ++l) {
        k_nr_layer<<<row_blocks, 256, 0, stream>>>(
            out, l * D_DIM, (l + 1) * D_DIM,
            row_ptr_adj, adj + T_TRI, r_index + T_TRI, r_val,
            rel_emb, norm_r, dotk + l * R_REL);
    }
    for (int l = 0; l < NDEPTH; ++l) {
        k_proj<<<row_blocks, 256, 0, stream>>>(
            out, (2 + l) * D_DIM, high_atts + l * D_DIM, proj);
        k_high_layer<<<row_blocks, 256, 0, stream>>>(
            out, (2 + l) * D_DIM, (3 + l) * D_DIM,
            row_ptr_high, high_nei + T_TRI, proj);
    }
}

// Round 2
// 317.845 us; speedup vs baseline: 1.5731x; 1.5731x over previous
//
#include <hip/hip_runtime.h>
#include <math.h>

#define N_NODES 100000
#define R_REL   1000
#define T_TRI   600000
#define D_DIM   128
#define NDEPTH  2
#define OUT_STRIDE (D_DIM * (2 * NDEPTH + 1))   // 640

__device__ __forceinline__ float wave_sum(float v) {
    #pragma unroll
    for (int off = 32; off > 0; off >>= 1) v += __shfl_xor(v, off);
    return v;
}
__device__ __forceinline__ float wave_max(float v) {
    #pragma unroll
    for (int off = 32; off > 0; off >>= 1) v = fmaxf(v, __shfl_xor(v, off));
    return v;
}
__device__ __forceinline__ float sub16_sum(float v) {
    v += __shfl_xor(v, 1); v += __shfl_xor(v, 2);
    v += __shfl_xor(v, 4); v += __shfl_xor(v, 8);
    return v;
}
__device__ __forceinline__ float4 tanh4(float4 v) {
    float4 o; o.x = tanhf(v.x); o.y = tanhf(v.y); o.z = tanhf(v.z); o.w = tanhf(v.w);
    return o;
}

// out[n, 0:128] = tanh(features[n, :])
__global__ void k_tanh(const float* __restrict__ feat, float* __restrict__ out) {
    int i = blockIdx.x * blockDim.x + threadIdx.x;          // over N*D/4
    if (i >= N_NODES * D_DIM / 4) return;
    int n  = i / (D_DIM / 4);
    int d4 = i % (D_DIM / 4);
    float4 v = reinterpret_cast<const float4*>(feat)[i];
    reinterpret_cast<float4*>(out + (size_t)n * OUT_STRIDE)[d4] = tanh4(v);
}

// per-relation: norm_r[r] = ||rel_emb[r]||,  dotk[l*R + r] = rel_emb[r] . attn_kernels[l]
__global__ void k_relprep(const float* __restrict__ rel, const float* __restrict__ attk,
                          float* __restrict__ norm_r, float* __restrict__ dotk) {
    int r = blockIdx.x;
    int lane = threadIdx.x;                                  // 64 threads
    float a0 = rel[r * D_DIM + lane], a1 = rel[r * D_DIM + 64 + lane];
    float nrm = wave_sum(a0 * a0 + a1 * a1);
    float d0  = wave_sum(a0 * attk[lane] + a1 * attk[64 + lane]);
    float d1  = wave_sum(a0 * attk[D_DIM + lane] + a1 * attk[D_DIM + 64 + lane]);
    if (lane == 0) {
        norm_r[r] = sqrtf(nrm);
        dotk[r] = d0;
        dotk[R_REL + r] = d1;
    }
}

// row_ptr[n] = lower_bound(rows, n) over sorted rows[0..T)
__global__ void k_rowptr(const int* __restrict__ rows, int* __restrict__ ptr) {
    int n = blockIdx.x * blockDim.x + threadIdx.x;
    if (n > N_NODES) return;
    int lo = 0, hi = T_TRI;
    while (lo < hi) { int mid = (lo + hi) >> 1; if (rows[mid] < n) lo = mid + 1; else hi = mid; }
    ptr[n] = lo;
}

// One wave per row.  Pass A: lane-parallel segment softmax stats (weights cached
// to LDS for deg<=64).  Pass B: 4 subgroups x 16 lanes, one triple per subgroup,
// 8 dims/lane; per-triple Householder dot is a 4-shuffle subgroup reduce.
// Optional fused epilogue: proj_out[row] = tanh(acc) . ha  (for next high layer).
__global__ __launch_bounds__(256) void k_nr_layer(
    float* __restrict__ outbuf, int in_off, int out_off,
    const int* __restrict__ row_ptr,
    const int* __restrict__ col,
    const int* __restrict__ ridx1,
    const float* __restrict__ r_val,
    const float* __restrict__ rel,
    const float* __restrict__ norm_r,
    const float* __restrict__ dotk,
    const float* __restrict__ ha,      // nullable: high_atts row for proj fusion
    float* __restrict__ proj_out) {
    __shared__ float s_w[4][64];
    __shared__ float s_sc[4][64];
    __shared__ int   s_rt[4][64];
    int wslot = threadIdx.x >> 6;
    int lane  = threadIdx.x & 63;
    int wid   = (blockIdx.x * blockDim.x + threadIdx.x) >> 6;
    if (wid >= N_NODES) return;
    int beg = row_ptr[wid], end = row_ptr[wid + 1];
    float* orow = outbuf + (size_t)wid * OUT_STRIDE + out_off;
    int sg = lane >> 4, sl = lane & 15;
    if (beg == end) {
        float4 z = {0.f, 0.f, 0.f, 0.f};
        if (sg == 0) ((float4*)orow)[sl] = z;
        else if (sg == 1) ((float4*)orow)[16 + sl] = z;
        if (ha != nullptr && lane == 0) proj_out[wid] = 0.f;
        return;
    }

    // ---- pass A: segment max / sumexp over scalar relation logits ----
    float l0 = 0.f, sc0 = 0.f; int rt0 = 0;
    float lmax = -INFINITY;
    int t0 = beg + lane;
    if (t0 < end) {
        rt0 = ridx1[t0]; float rv = r_val[t0];
        sc0 = rv / fmaxf(rv * norm_r[rt0], 1e-12f);
        l0  = sc0 * dotk[rt0];
        lmax = l0;
    }
    for (int t = t0 + 64; t < end; t += 64) {
        int rt = ridx1[t]; float rv = r_val[t];
        float sc = rv / fmaxf(rv * norm_r[rt], 1e-12f);
        lmax = fmaxf(lmax, sc * dotk[rt]);
    }
    float m = wave_max(lmax);
    float e0 = (t0 < end) ? expf(l0 - m) : 0.f;
    float lsum = e0;
    for (int t = t0 + 64; t < end; t += 64) {
        int rt = ridx1[t]; float rv = r_val[t];
        float sc = rv / fmaxf(rv * norm_r[rt], 1e-12f);
        lsum += expf(sc * dotk[rt] - m);
    }
    float inv_s = 1.f / wave_sum(lsum);
    s_w[wslot][lane]  = e0 * inv_s;   // valid for idx<64 (idx = t-beg)
    s_sc[wslot][lane] = sc0;
    s_rt[wslot][lane] = rt0;
    // same wave: no barrier needed

    // ---- pass B: subgroup-parallel weighted reflected accumulate ----
    float4 accA = {0.f, 0.f, 0.f, 0.f}, accB = {0.f, 0.f, 0.f, 0.f};
    for (int t = beg + sg; t < end; t += 4) {
        int idx = t - beg;
        int rt; float w, sc;
        if (idx < 64) {
            w  = s_w[wslot][idx];
            sc = s_sc[wslot][idx];
            rt = s_rt[wslot][idx];
        } else {
            rt = ridx1[t]; float rv = r_val[t];
            sc = rv / fmaxf(rv * norm_r[rt], 1e-12f);
            w  = expf(sc * dotk[rt] - m) * inv_s;
        }
        int c = col[t];
        const float4* frow4 = (const float4*)(outbuf + (size_t)c * OUT_STRIDE + in_off);
        const float4* rrow4 = (const float4*)(rel + (size_t)rt * D_DIM);
        float4 n0 = frow4[sl],     n1 = frow4[16 + sl];
        float4 r0 = rrow4[sl],     r1 = rrow4[16 + sl];
        float pd = n0.x * r0.x + n0.y * r0.y + n0.z * r0.z + n0.w * r0.w
                 + n1.x * r1.x + n1.y * r1.y + n1.z * r1.z + n1.w * r1.w;
        pd = sub16_sum(pd);                 // full-D dot within the 16-lane subgroup
        float f = 2.f * sc * sc * pd;
        accA.x += w * (n0.x - f * r0.x); accA.y += w * (n0.y - f * r0.y);
        accA.z += w * (n0.z - f * r0.z); accA.w += w * (n0.w - f * r0.w);
        accB.x += w * (n1.x - f * r1.x); accB.y += w * (n1.y - f * r1.y);
        accB.z += w * (n1.z - f * r1.z); accB.w += w * (n1.w - f * r1.w);
    }
    // combine the 4 subgroup partials (lanes l, l+16, l+32, l+48 share dims)
#define CMB(c) { c += __shfl_xor(c, 16); c += __shfl_xor(c, 32); }
    CMB(accA.x) CMB(accA.y) CMB(accA.z) CMB(accA.w)
    CMB(accB.x) CMB(accB.y) CMB(accB.z) CMB(accB.w)
#undef CMB
    float4 tA = tanh4(accA), tB = tanh4(accB);
    if (sg == 0) ((float4*)orow)[sl] = tA;
    else if (sg == 1) ((float4*)orow)[16 + sl] = tB;
    if (ha != nullptr) {
        const float4* ha4 = (const float4*)ha;
        float4 h0 = ha4[sl], h1 = ha4[16 + sl];
        float pd = tA.x * h0.x + tA.y * h0.y + tA.z * h0.z + tA.w * h0.w
                 + tB.x * h1.x + tB.y * h1.y + tB.z * h1.z + tB.w * h1.w;
        pd = sub16_sum(pd);                 // all subgroups identical; reduce 16 lanes
        if (lane == 0) proj_out[wid] = pd;
    }
}

__global__ __launch_bounds__(256) void k_high_layer(
    float* __restrict__ outbuf, int in_off, int out_off,
    const int* __restrict__ row_ptr,
    const int* __restrict__ hcol,
    const float* __restrict__ proj,
    const float* __restrict__ ha,      // nullable: high_atts row for next proj
    float* __restrict__ proj_out) {
    __shared__ float s_w[4][64];
    int wslot = threadIdx.x >> 6;
    int lane  = threadIdx.x & 63;
    int wid   = (blockIdx.x * blockDim.x + threadIdx.x) >> 6;
    if (wid >= N_NODES) return;
    int beg = row_ptr[wid], end = row_ptr[wid + 1];
    float* orow = outbuf + (size_t)wid * OUT_STRIDE + out_off;
    int sg = lane >> 4, sl = lane & 15;
    if (beg == end) {
        float4 z = {0.f, 0.f, 0.f, 0.f};
        if (sg == 0) ((float4*)orow)[sl] = z;
        else if (sg == 1) ((float4*)orow)[16 + sl] = z;
        if (ha != nullptr && lane == 0) proj_out[wid] = 0.f;
        return;
    }
    int t0 = beg + lane;
    float l0 = (t0 < end) ? proj[hcol[t0]] : -INFINITY;
    float lmax = l0;
    for (int t = t0 + 64; t < end; t += 64)
        lmax = fmaxf(lmax, proj[hcol[t]]);
    float m = wave_max(lmax);
    float e0 = (t0 < end) ? expf(l0 - m) : 0.f;
    float lsum = e0;
    for (int t = t0 + 64; t < end; t += 64)
        lsum += expf(proj[hcol[t]] - m);
    float inv_s = 1.f / wave_sum(lsum);
    s_w[wslot][lane] = e0 * inv_s;

    float4 accA = {0.f, 0.f, 0.f, 0.f}, accB = {0.f, 0.f, 0.f, 0.f};
    for (int t = beg + sg; t < end; t += 4) {
        int idx = t - beg;
        int c = hcol[t];
        float w = (idx < 64) ? s_w[wslot][idx] : expf(proj[c] - m) * inv_s;
        const float4* frow4 = (const float4*)(outbuf + (size_t)c * OUT_STRIDE + in_off);
        float4 n0 = frow4[sl], n1 = frow4[16 + sl];
        accA.x += w * n0.x; accA.y += w * n0.y; accA.z += w * n0.z; accA.w += w * n0.w;
        accB.x += w * n1.x; accB.y += w * n1.y; accB.z += w * n1.z; accB.w += w * n1.w;
    }
#define CMB(c) { c += __shfl_xor(c, 16); c += __shfl_xor(c, 32); }
    CMB(accA.x) CMB(accA.y) CMB(accA.z) CMB(accA.w)
    CMB(accB.x) CMB(accB.y) CMB(accB.z) CMB(accB.w)
#undef CMB
    float4 tA = tanh4(accA), tB = tanh4(accB);
    if (sg == 0) ((float4*)orow)[sl] = tA;
    else if (sg == 1) ((float4*)orow)[16 + sl] = tB;
    if (ha != nullptr) {
        const float4* ha4 = (const float4*)ha;
        float4 h0 = ha4[sl], h1 = ha4[16 + sl];
        float pd = tA.x * h0.x + tA.y * h0.y + tA.z * h0.z + tA.w * h0.w
                 + tB.x * h1.x + tB.y * h1.y + tB.z * h1.z + tB.w * h1.w;
        pd = sub16_sum(pd);
        if (lane == 0) proj_out[wid] = pd;
    }
}

extern "C" void kernel_launch(void* const* d_in, const int* in_sizes, int n_in,
                              void* d_out, int out_size, void* d_ws, size_t ws_size,
                              hipStream_t stream) {
    const float* features  = (const float*)d_in[0];
    const float* rel_emb   = (const float*)d_in[1];
    const float* r_val     = (const float*)d_in[2];
    const float* attk      = (const float*)d_in[3];
    const float* high_atts = (const float*)d_in[4];
    const int*   adj       = (const int*)d_in[5];   // [0..T) = row, [T..2T) = col
    const int*   r_index   = (const int*)d_in[6];   // [0..T) = arange, [T..2T) = rel id
    const int*   high_nei  = (const int*)d_in[7];
    float* out = (float*)d_out;

    char* ws = (char*)d_ws;
    int*   row_ptr_adj  = (int*)ws;   ws += (N_NODES + 1) * sizeof(int);
    int*   row_ptr_high = (int*)ws;   ws += (N_NODES + 1) * sizeof(int);
    float* norm_r       = (float*)ws; ws += R_REL * sizeof(float);
    float* dotk         = (float*)ws; ws += 2 * R_REL * sizeof(float);
    float* proj0        = (float*)ws; ws += N_NODES * sizeof(float);
    float* proj1        = (float*)ws; ws += N_NODES * sizeof(float);

    k_tanh<<<(N_NODES * D_DIM / 4 + 255) / 256, 256, 0, stream>>>(features, out);
    k_relprep<<<R_REL, 64, 0, stream>>>(rel_emb, attk, norm_r, dotk);
    k_rowptr<<<(N_NODES + 256) / 256, 256, 0, stream>>>(adj, row_ptr_adj);
    k_rowptr<<<(N_NODES + 256) / 256, 256, 0, stream>>>(high_nei, row_ptr_high);

    int row_blocks = (N_NODES + 3) / 4;     // 4 waves (rows) per 256-thread block

    // NR layer 0: chunk0 -> chunk1 (no proj fusion)
    k_nr_layer<<<row_blocks, 256, 0, stream>>>(
        out, 0 * D_DIM, 1 * D_DIM,
        row_ptr_adj, adj + T_TRI, r_index + T_TRI, r_val,
        rel_emb, norm_r, dotk + 0 * R_REL, nullptr, nullptr);
    // NR layer 1: chunk1 -> chunk2, fuse proj0 = chunk2 . high_atts[0]
    k_nr_layer<<<row_blocks, 256, 0, stream>>>(
        out, 1 * D_DIM, 2 * D_DIM,
        row_ptr_adj, adj + T_TRI, r_index + T_TRI, r_val,
        rel_emb, norm_r, dotk + 1 * R_REL, high_atts + 0 * D_DIM, proj0);
    // High layer 0: chunk2 -> chunk3, uses proj0; fuse proj1 = chunk3 . high_atts[1]
    k_high_layer<<<row_blocks, 256, 0, stream>>>(
        out, 2 * D_DIM, 3 * D_DIM,
        row_ptr_high, high_nei + T_TRI, proj0, high_atts + 1 * D_DIM, proj1);
    // High layer 1: chunk3 -> chunk4, uses proj1
    k_high_layer<<<row_blocks, 256, 0, stream>>>(
        out, 3 * D_DIM, 4 * D_DIM,
        row_ptr_high, high_nei + T_TRI, proj1, nullptr, nullptr);
}